// Round 9
// baseline (168.434 us; speedup 1.0000x reference)
//
#include <hip/hip_runtime.h>
#include <math.h>

#define NT 256

typedef __attribute__((ext_vector_type(8))) short short8;
typedef __attribute__((ext_vector_type(4))) float f32x4;
typedef unsigned short ushort_t;

__device__ __forceinline__ float sigmoidf_(float x){ return 1.0f/(1.0f+__expf(-x)); }
__device__ __forceinline__ ushort_t f2bf(float x){
  unsigned int u = __float_as_uint(x);
  u = u + 0x7fff + ((u>>16)&1);
  return (ushort_t)(u>>16);
}
__device__ __forceinline__ float bf2f(ushort_t b){
  return __uint_as_float(((unsigned int)b)<<16);
}

// ---- PE: weight prep (grid-stride) + embed (16 rows/block). 512 blocks. ----
__global__ __launch_bounds__(256) void k_pe(
    const float* __restrict__ jets, const float* __restrict__ W_emb,
    const float* __restrict__ b_emb, const float* __restrict__ w_edge,
    const float* __restrict__ Wi, const float* __restrict__ bi,
    const float* __restrict__ Wh, const float* __restrict__ Wr1,
    ushort_t* __restrict__ hbf0, ushort_t* __restrict__ gjets,
    ushort_t* __restrict__ WiMtB, ushort_t* __restrict__ WhB,
    ushort_t* __restrict__ Wr1T, float* __restrict__ s_part)
{
  int t = threadIdx.x, blk = blockIdx.x;
  int gid = blk*NT + t, gstride = gridDim.x*NT;
  for (int e=gid; e<256*768; e+=gstride){ int k=e/768, row=e-k*768; WiMtB[e]=f2bf(Wi[(size_t)row*264 + k]); }
  for (int e=gid; e<768*256; e+=gstride){ WhB[e]=f2bf(Wh[e]); }
  for (int e=gid; e<256*256; e+=gstride){ int n=e>>8, k=e&255; Wr1T[e]=f2bf(Wr1[(size_t)k*256+n]); }
  int lane = t & 63, w = t >> 6;
  #pragma unroll
  for (int v=0; v<4; ++v){
    int m = blk*16 + w*4 + v;
    float jr[8];
    #pragma unroll
    for (int f=0; f<8; ++f) jr[f] = jets[m*8+f];
    float sp = 0.f;
    #pragma unroll
    for (int u=0; u<4; ++u){
      int c = lane + 64*u;
      float a = b_emb[c];
      #pragma unroll
      for (int f=0; f<8; ++f) a = fmaf(jr[f], W_emb[f*256+c], a);
      float hv = tanhf(a);
      hbf0[(size_t)m*256 + c] = f2bf(hv);
      sp = fmaf(hv, w_edge[c], sp);
    }
    sp += __shfl_xor(sp,1); sp += __shfl_xor(sp,2); sp += __shfl_xor(sp,4);
    sp += __shfl_xor(sp,8); sp += __shfl_xor(sp,16); sp += __shfl_xor(sp,32);
    if (lane==0) s_part[m] = sp;
    else if (lane<8) s_part[lane*8192 + m] = 0.f;
    #pragma unroll
    for (int g=0; g<3; ++g){
      #pragma unroll
      for (int u=0; u<4; ++u){
        int c = lane + 64*u;
        int rowi = g*256 + c;
        float acc = bi[rowi];
        #pragma unroll
        for (int f=0; f<8; ++f) acc = fmaf(jr[f], Wi[(size_t)rowi*264 + 256 + f], acc);
        gjets[(size_t)m*768 + rowi] = f2bf(acc);
      }
    }
  }
}

// ---- hbar partials: 256 blocks = (batch, j-chunk); writes its own slot ----
__global__ __launch_bounds__(256) void k_hbar(const ushort_t* __restrict__ hbf,
    const float* __restrict__ s_part, float* __restrict__ hbar_p){
  int t = threadIdx.x;
  int b = blockIdx.x >> 3, js = blockIdx.x & 7;
  int jc = js << 5;
  __shared__ float eS[256], red[256];
  float s_t = 0.f;
  #pragma unroll
  for (int sl=0; sl<8; ++sl) s_t += s_part[sl*8192 + b*256 + t];
  red[t] = s_t; __syncthreads();
  for (int o=128;o>0;o>>=1){ if (t<o) red[t]=fmaxf(red[t],red[t+o]); __syncthreads(); }
  float mx = red[0]; __syncthreads();
  float e = __expf(s_t-mx); eS[t]=e; red[t]=e; __syncthreads();
  for (int o=128;o>0;o>>=1){ if (t<o) red[t]+=red[t+o]; __syncthreads(); }
  float rZ = 1.0f/red[0];
  const ushort_t* hb = hbf + (size_t)b*256*256;
  float p = 0.f;
  #pragma unroll
  for (int j=0;j<32;++j)
    p = fmaf(eS[jc+j], bf2f(hb[(size_t)(jc+j)*256 + t]), p);
  hbar_p[js*8192 + b*256 + t] = p*rZ;
}

// ---- msg partials: 256 blocks = (batch, k-slice of 32). f32, coalesced ----
__global__ __launch_bounds__(256) void k_msgp(const float* __restrict__ hbar_p,
    const float* __restrict__ W_msg, float* __restrict__ msg_p){
  int t = threadIdx.x;
  int b = blockIdx.x >> 3, ks = blockIdx.x & 7;
  __shared__ float hch[32];
  if (t < 32){
    float v = 0.f;
    #pragma unroll
    for (int sl=0; sl<8; ++sl) v += hbar_p[sl*8192 + b*256 + ks*32 + t];
    hch[t] = v;
  }
  __syncthreads();
  float acc = 0.f;
  #pragma unroll
  for (int k=0; k<32; ++k)
    acc = fmaf(hch[k], W_msg[(size_t)(ks*32+k)*256 + t], acc);
  msg_p[ks*8192 + b*256 + t] = acc;
}

// ---- GRU via MFMA, no A/B LDS staging (direct short8 fragment loads),
//      gmsg strip computed in prologue from msg_p slots. 512 blocks. ----
__global__ __launch_bounds__(256) void k_gru_mfma(
    const ushort_t* __restrict__ hbf_in,
    const ushort_t* __restrict__ WhB, const float* __restrict__ bh,
    const ushort_t* __restrict__ gjets, const float* __restrict__ msg_p,
    const float* __restrict__ b_msg, const ushort_t* __restrict__ WiMtB,
    const float* __restrict__ w_edge,
    ushort_t* __restrict__ hbf_out, float* __restrict__ s_part, int compute_s)
{
  __shared__ float mvS[256];
  __shared__ float gm_s[192], bh_s[192];
  int t = threadIdx.x;
  int hcb = blockIdx.x & 3, mblk = blockIdx.x >> 2;
  int m0 = mblk*64, hc0 = hcb*64, b = m0 >> 8;
  // mv = tanh(b_msg + sum of msg_p slots)
  {
    float v = b_msg[t];
    #pragma unroll
    for (int sl=0; sl<8; ++sl) v += msg_p[sl*8192 + b*256 + t];
    mvS[t] = tanhf(v);
  }
  __syncthreads();
  // gmsg strip for this block: 192 outputs, k=256 (waves 0-2; wave 3 idles)
  if (t < 192){
    int g = t>>6, c = t&63;
    int rowi = g*256 + hc0 + c;
    float acc = 0.f;
    #pragma unroll 8
    for (int k=0; k<256; ++k)
      acc = fmaf(mvS[k], bf2f(WiMtB[(size_t)k*768 + rowi]), acc);
    gm_s[t] = acc;
    bh_s[t] = bh[rowi];
  }
  int lane = t & 63, w = t >> 6;
  int wr = w >> 1, wc = w & 1;
  int q = lane >> 4, r = lane & 15;
  f32x4 acc[3][2][2] = {};
  #pragma unroll
  for (int kt = 0; kt < 8; ++kt){
    short8 af[2], bfr[3][2];
    #pragma unroll
    for (int fm=0; fm<2; ++fm)
      af[fm] = *(const short8*)&hbf_in[(size_t)(m0 + wr*32 + fm*16 + r)*256 + kt*32 + q*8];
    #pragma unroll
    for (int g=0; g<3; ++g)
      #pragma unroll
      for (int fn=0; fn<2; ++fn)
        bfr[g][fn] = *(const short8*)&WhB[(size_t)(g*256 + hc0 + wc*32 + fn*16 + r)*256 + kt*32 + q*8];
    #pragma unroll
    for (int g=0; g<3; ++g)
      #pragma unroll
      for (int fm=0; fm<2; ++fm)
        #pragma unroll
        for (int fn=0; fn<2; ++fn)
          acc[g][fm][fn] = __builtin_amdgcn_mfma_f32_16x16x32_bf16(af[fm], bfr[g][fn], acc[g][fm][fn], 0,0,0);
  }
  __syncthreads();   // gm_s/bh_s ready for all waves before epilogue
  float wef[2];
  wef[0] = w_edge[hc0 + wc*32 + r];
  wef[1] = w_edge[hc0 + wc*32 + 16 + r];
  float pacc[2][4] = {};
  #pragma unroll
  for (int fm=0; fm<2; ++fm)
    #pragma unroll
    for (int fn=0; fn<2; ++fn){
      int cloc = wc*32 + fn*16 + r;
      int hcol = hc0 + cloc;
      #pragma unroll
      for (int jj=0; jj<4; ++jj){
        int m = m0 + wr*32 + fm*16 + q*4 + jj;
        float gir = bf2f(gjets[(size_t)m*768 + hcol])       + gm_s[cloc];
        float giz = bf2f(gjets[(size_t)m*768 + 256 + hcol]) + gm_s[64+cloc];
        float gin = bf2f(gjets[(size_t)m*768 + 512 + hcol]) + gm_s[128+cloc];
        float rr = sigmoidf_(gir + acc[0][fm][fn][jj] + bh_s[cloc]);
        float zz = sigmoidf_(giz + acc[1][fm][fn][jj] + bh_s[64+cloc]);
        float nn = tanhf(gin + rr*(acc[2][fm][fn][jj] + bh_s[128+cloc]));
        float ho = bf2f(hbf_in[(size_t)m*256 + hcol]);
        float hn = (1.f - zz)*nn + zz*ho;
        hbf_out[(size_t)m*256 + hcol] = f2bf(hn);
        pacc[fm][jj] = fmaf(wef[fn], hn, pacc[fm][jj]);
      }
    }
  if (compute_s){
    #pragma unroll
    for (int fm=0; fm<2; ++fm)
      #pragma unroll
      for (int jj=0; jj<4; ++jj){
        float p = pacc[fm][jj];
        p += __shfl_xor(p,1); p += __shfl_xor(p,2);
        p += __shfl_xor(p,4); p += __shfl_xor(p,8);
        if (r == 0)
          s_part[(hcb*2 + wc)*8192 + m0 + wr*32 + fm*16 + q*4 + jj] = p;
      }
  }
}

// ---- readout MFMA, no LDS staging: slot partial writes. 512 blocks ----
__global__ __launch_bounds__(256) void k_ro(
    const ushort_t* __restrict__ hbf, const ushort_t* __restrict__ Wr1T,
    const float* __restrict__ br1, float* __restrict__ zsum_p)
{
  int t = threadIdx.x;
  int ncb = blockIdx.x & 3, mblk = blockIdx.x >> 2;
  int m0 = mblk*64, nc0 = ncb*64, b = m0 >> 8;
  int lane = t & 63, w = t >> 6;
  int wr = w >> 1, wc = w & 1;
  int q = lane >> 4, r = lane & 15;
  f32x4 acc[2][2] = {};
  #pragma unroll
  for (int kt = 0; kt < 8; ++kt){
    short8 af[2], bfr[2];
    #pragma unroll
    for (int fm=0; fm<2; ++fm)
      af[fm] = *(const short8*)&hbf[(size_t)(m0 + wr*32 + fm*16 + r)*256 + kt*32 + q*8];
    #pragma unroll
    for (int fn=0; fn<2; ++fn)
      bfr[fn] = *(const short8*)&Wr1T[(size_t)(nc0 + wc*32 + fn*16 + r)*256 + kt*32 + q*8];
    #pragma unroll
    for (int fm=0; fm<2; ++fm)
      #pragma unroll
      for (int fn=0; fn<2; ++fn)
        acc[fm][fn] = __builtin_amdgcn_mfma_f32_16x16x32_bf16(af[fm], bfr[fn], acc[fm][fn], 0,0,0);
  }
  #pragma unroll
  for (int fn=0; fn<2; ++fn){
    int n = nc0 + wc*32 + fn*16 + r;
    float bb = br1[n];
    float cs = 0.f;
    #pragma unroll
    for (int fm=0; fm<2; ++fm)
      #pragma unroll
      for (int jj=0; jj<4; ++jj)
        cs += fmaxf(acc[fm][fn][jj] + bb, 0.f);
    cs += __shfl_xor(cs, 16);
    cs += __shfl_xor(cs, 32);
    if (q == 0) zsum_p[((mblk&3)*2 + wr)*8192 + b*256 + n] = cs;
  }
}

// ---- final: out[b,:] = (Σ slots zsum)[b,:] @ Wr2 + N*br2. 32 blocks ----
__global__ __launch_bounds__(256) void k_fin(const float* __restrict__ zsum_p,
    const float* __restrict__ Wr2, const float* __restrict__ br2,
    float* __restrict__ out){
  int b = blockIdx.x, t = threadIdx.x;
  __shared__ float zs[256];
  float z = 0.f;
  #pragma unroll
  for (int sl=0; sl<8; ++sl) z += zsum_p[sl*8192 + b*256 + t];
  zs[t] = z; __syncthreads();
  float acc = 0.f;
  for (int k=0;k<256;++k) acc = fmaf(zs[k], Wr2[k*256 + t], acc);
  out[b*256 + t] = acc + 256.0f*br2[t];
}

extern "C" void kernel_launch(void* const* d_in, const int* in_sizes, int n_in,
                              void* d_out, int out_size, void* d_ws, size_t ws_size,
                              hipStream_t stream){
  (void)in_sizes; (void)n_in; (void)out_size; (void)ws_size;
  const float* jets  = (const float*)d_in[0];
  const float* W_emb = (const float*)d_in[1];
  const float* b_emb = (const float*)d_in[2];
  const float* w_edge= (const float*)d_in[3];
  // d_in[4] = b_edge: cancels in softmax
  const float* W_msg = (const float*)d_in[5];
  const float* b_msg = (const float*)d_in[6];
  const float* Wi    = (const float*)d_in[7];
  const float* bi    = (const float*)d_in[8];
  const float* Wh    = (const float*)d_in[9];
  const float* bh    = (const float*)d_in[10];
  const float* Wr1   = (const float*)d_in[11];
  const float* br1   = (const float*)d_in[12];
  const float* Wr2   = (const float*)d_in[13];
  const float* br2   = (const float*)d_in[14];
  float* out = (float*)d_out;
  float* ws  = (float*)d_ws;
  // workspace layout (float-slot units)
  ushort_t* hbf0  = (ushort_t*)ws;                  // 1,048,576 f
  ushort_t* hbf1  = (ushort_t*)(ws + 1048576);      // 1,048,576 f
  ushort_t* gjets = (ushort_t*)(ws + 2097152);      // 3,145,728 f
  ushort_t* WiMtB = (ushort_t*)(ws + 5242880);      // 98,304 f  [k=256][row=768] bf16
  ushort_t* WhB   = (ushort_t*)(ws + 5341184);      // 98,304 f
  ushort_t* Wr1T  = (ushort_t*)(ws + 5439488);      // 32,768 f
  float* s_part   = ws + 5472256;                   // [8][8192]
  float* hbar_p   = ws + 5537792;                   // [8][8192]
  float* msg_p    = ws + 5603328;                   // [8][8192]
  float* zsum_p   = ws + 5668864;                   // [8][8192] (end 5,734,400 f = 22.9MB)
  ushort_t* hbf[2] = {hbf0, hbf1};

  k_pe<<<512,NT,0,stream>>>(jets, W_emb, b_emb, w_edge, Wi, bi, Wh, Wr1,
                            hbf[0], gjets, WiMtB, WhB, Wr1T, s_part);
  for (int it=0; it<3; ++it){
    int cur = it & 1, nxt = cur ^ 1;
    k_hbar<<<256,NT,0,stream>>>(hbf[cur], s_part, hbar_p);
    k_msgp<<<256,NT,0,stream>>>(hbar_p, W_msg, msg_p);
    k_gru_mfma<<<512,NT,0,stream>>>(hbf[cur], WhB, bh, gjets, msg_p, b_msg,
                                    WiMtB, w_edge, hbf[nxt], s_part, (it<2)?1:0);
  }
  k_ro<<<512,NT,0,stream>>>(hbf[1], Wr1T, br1, zsum_p);
  k_fin<<<32,NT,0,stream>>>(zsum_p, Wr2, br2, out);
}

// Round 10
// 125.015 us; speedup vs baseline: 1.3473x; 1.3473x over previous
//
#include <hip/hip_runtime.h>
#include <math.h>

#define NT 256

typedef __attribute__((ext_vector_type(8))) short short8;
typedef __attribute__((ext_vector_type(4))) float f32x4;
typedef unsigned short ushort_t;

__device__ __forceinline__ float sigmoidf_(float x){ return 1.0f/(1.0f+__expf(-x)); }
__device__ __forceinline__ ushort_t f2bf(float x){
  unsigned int u = __float_as_uint(x);
  u = u + 0x7fff + ((u>>16)&1);
  return (ushort_t)(u>>16);
}
__device__ __forceinline__ float bf2f(ushort_t b){
  return __uint_as_float(((unsigned int)b)<<16);
}

// LDS tile row pitch: 40 shorts (80B). ds_read_b128 bank = (row*20+q*4)%32:
// rows alias only at distance 8 -> 2-way (free, m136). 32-pitch was 8-way.
#define APITCH 40

// ---- PE: weight prep (grid-stride) + embed (16 rows/block). 512 blocks. ----
__global__ __launch_bounds__(256) void k_pe(
    const float* __restrict__ jets, const float* __restrict__ W_emb,
    const float* __restrict__ b_emb, const float* __restrict__ w_edge,
    const float* __restrict__ Wi, const float* __restrict__ bi,
    const float* __restrict__ Wh, const float* __restrict__ Wr1,
    ushort_t* __restrict__ hbf0, ushort_t* __restrict__ gjets,
    float* __restrict__ WiMt, ushort_t* __restrict__ WhB,
    ushort_t* __restrict__ Wr1T, float* __restrict__ s_part)
{
  int t = threadIdx.x, blk = blockIdx.x;
  int gid = blk*NT + t, gstride = gridDim.x*NT;
  for (int e=gid; e<256*768; e+=gstride){ int k=e/768, row=e-k*768; WiMt[e]=Wi[(size_t)row*264 + k]; }
  for (int e=gid; e<768*256; e+=gstride){ WhB[e]=f2bf(Wh[e]); }
  for (int e=gid; e<256*256; e+=gstride){ int n=e>>8, k=e&255; Wr1T[e]=f2bf(Wr1[(size_t)k*256+n]); }
  int lane = t & 63, w = t >> 6;
  #pragma unroll
  for (int v=0; v<4; ++v){
    int m = blk*16 + w*4 + v;
    float jr[8];
    #pragma unroll
    for (int f=0; f<8; ++f) jr[f] = jets[m*8+f];
    float sp = 0.f;
    #pragma unroll
    for (int u=0; u<4; ++u){
      int c = lane + 64*u;
      float a = b_emb[c];
      #pragma unroll
      for (int f=0; f<8; ++f) a = fmaf(jr[f], W_emb[f*256+c], a);
      float hv = tanhf(a);
      hbf0[(size_t)m*256 + c] = f2bf(hv);
      sp = fmaf(hv, w_edge[c], sp);
    }
    sp += __shfl_xor(sp,1); sp += __shfl_xor(sp,2); sp += __shfl_xor(sp,4);
    sp += __shfl_xor(sp,8); sp += __shfl_xor(sp,16); sp += __shfl_xor(sp,32);
    if (lane==0) s_part[m] = sp;
    else if (lane<8) s_part[lane*8192 + m] = 0.f;
    #pragma unroll
    for (int g=0; g<3; ++g){
      #pragma unroll
      for (int u=0; u<4; ++u){
        int c = lane + 64*u;
        int rowi = g*256 + c;
        float acc = bi[rowi];
        #pragma unroll
        for (int f=0; f<8; ++f) acc = fmaf(jr[f], Wi[(size_t)rowi*264 + 256 + f], acc);
        gjets[(size_t)m*768 + rowi] = f2bf(acc);
      }
    }
  }
}

// ---- hbar partials: 256 blocks = (batch, j-chunk); writes its own slot ----
__global__ __launch_bounds__(256) void k_hbar(const ushort_t* __restrict__ hbf,
    const float* __restrict__ s_part, float* __restrict__ hbar_p){
  int t = threadIdx.x;
  int b = blockIdx.x >> 3, js = blockIdx.x & 7;
  int jc = js << 5;
  __shared__ float eS[256], red[256];
  float s_t = 0.f;
  #pragma unroll
  for (int sl=0; sl<8; ++sl) s_t += s_part[sl*8192 + b*256 + t];
  red[t] = s_t; __syncthreads();
  for (int o=128;o>0;o>>=1){ if (t<o) red[t]=fmaxf(red[t],red[t+o]); __syncthreads(); }
  float mx = red[0]; __syncthreads();
  float e = __expf(s_t-mx); eS[t]=e; red[t]=e; __syncthreads();
  for (int o=128;o>0;o>>=1){ if (t<o) red[t]+=red[t+o]; __syncthreads(); }
  float rZ = 1.0f/red[0];
  const ushort_t* hb = hbf + (size_t)b*256*256;
  float p = 0.f;
  #pragma unroll
  for (int j=0;j<32;++j)
    p = fmaf(eS[jc+j], bf2f(hb[(size_t)(jc+j)*256 + t]), p);
  hbar_p[js*8192 + b*256 + t] = p*rZ;
}

// ---- msg partials: 256 blocks = (batch, k-slice of 32). f32, coalesced ----
__global__ __launch_bounds__(256) void k_msgp(const float* __restrict__ hbar_p,
    const float* __restrict__ W_msg, float* __restrict__ msg_p){
  int t = threadIdx.x;
  int b = blockIdx.x >> 3, ks = blockIdx.x & 7;
  __shared__ float hch[32];
  if (t < 32){
    float v = 0.f;
    #pragma unroll
    for (int sl=0; sl<8; ++sl) v += hbar_p[sl*8192 + b*256 + ks*32 + t];
    hch[t] = v;
  }
  __syncthreads();
  float acc = 0.f;
  #pragma unroll
  for (int k=0; k<32; ++k)
    acc = fmaf(hch[k], W_msg[(size_t)(ks*32+k)*256 + t], acc);
  msg_p[ks*8192 + b*256 + t] = acc;
}

// ---- gmsg partials: 256 blocks = (batch, k-slice). mv=tanh(sum+bias) local ----
__global__ __launch_bounds__(256) void k_gmsgp(const float* __restrict__ msg_p,
    const float* __restrict__ b_msg, const float* __restrict__ WiMt,
    float* __restrict__ gmsg_p){
  int t = threadIdx.x;
  int b = blockIdx.x >> 3, ks = blockIdx.x & 7;
  __shared__ float mch[32];
  if (t < 32){
    float v = b_msg[ks*32 + t];
    #pragma unroll
    for (int sl=0; sl<8; ++sl) v += msg_p[sl*8192 + b*256 + ks*32 + t];
    mch[t] = tanhf(v);
  }
  __syncthreads();
  float a0=0.f, a1=0.f, a2=0.f;
  #pragma unroll
  for (int k=0; k<32; ++k){
    float m = mch[k];
    const float* wr = &WiMt[(size_t)(ks*32+k)*768 + t];
    a0 = fmaf(m, wr[0],   a0);
    a1 = fmaf(m, wr[256], a1);
    a2 = fmaf(m, wr[512], a2);
  }
  float* gp = &gmsg_p[(size_t)ks*24576 + (size_t)b*768 + t];
  gp[0] = a0; gp[256] = a1; gp[512] = a2;
}

// ---- GRU via MFMA + fused epilogue + s_part slot writes. 512 blocks ----
__global__ __launch_bounds__(256) void k_gru_mfma(
    const ushort_t* __restrict__ hbf_in,
    const ushort_t* __restrict__ WhB, const float* __restrict__ bh,
    const ushort_t* __restrict__ gjets, const float* __restrict__ gmsg_p,
    const float* __restrict__ w_edge,
    ushort_t* __restrict__ hbf_out, float* __restrict__ s_part, int compute_s)
{
  __shared__ __align__(16) short As[64*APITCH];
  __shared__ __align__(16) short Bs[3*64*APITCH];
  __shared__ float gm_s[192], bh_s[192];
  int t = threadIdx.x;
  int hcb = blockIdx.x & 3, mblk = blockIdx.x >> 2;
  int m0 = mblk*64, hc0 = hcb*64, b = m0 >> 8;
  if (t < 192){
    int g = t>>6, c = t&63;
    int rowi = g*256 + hc0 + c;
    float acc = 0.f;
    #pragma unroll
    for (int sl=0; sl<8; ++sl) acc += gmsg_p[(size_t)sl*24576 + (size_t)b*768 + rowi];
    gm_s[t] = acc;
    bh_s[t] = bh[rowi];
  }
  int lane = t & 63, w = t >> 6;
  int wr = w >> 1, wc = w & 1;
  int q = lane >> 4, r = lane & 15;
  int srow = t >> 2, sseg = t & 3;
  f32x4 acc[3][2][2] = {};
  for (int kt = 0; kt < 8; ++kt){
    __syncthreads();
    *(uint4*)&As[srow*APITCH + sseg*8] = *(const uint4*)&hbf_in[(size_t)(m0+srow)*256 + kt*32 + sseg*8];
    #pragma unroll
    for (int g = 0; g < 3; ++g)
      *(uint4*)&Bs[g*64*APITCH + srow*APITCH + sseg*8] = *(const uint4*)&WhB[(size_t)(g*256 + hc0 + srow)*256 + kt*32 + sseg*8];
    __syncthreads();
    short8 af[2], bfr[3][2];
    #pragma unroll
    for (int fm=0; fm<2; ++fm)
      af[fm] = *(const short8*)&As[(wr*32 + fm*16 + r)*APITCH + q*8];
    #pragma unroll
    for (int g=0; g<3; ++g)
      #pragma unroll
      for (int fn=0; fn<2; ++fn)
        bfr[g][fn] = *(const short8*)&Bs[g*64*APITCH + (wc*32 + fn*16 + r)*APITCH + q*8];
    #pragma unroll
    for (int g=0; g<3; ++g)
      #pragma unroll
      for (int fm=0; fm<2; ++fm)
        #pragma unroll
        for (int fn=0; fn<2; ++fn)
          acc[g][fm][fn] = __builtin_amdgcn_mfma_f32_16x16x32_bf16(af[fm], bfr[g][fn], acc[g][fm][fn], 0,0,0);
  }
  float wef[2];
  wef[0] = w_edge[hc0 + wc*32 + r];
  wef[1] = w_edge[hc0 + wc*32 + 16 + r];
  float pacc[2][4] = {};
  #pragma unroll
  for (int fm=0; fm<2; ++fm)
    #pragma unroll
    for (int fn=0; fn<2; ++fn){
      int cloc = wc*32 + fn*16 + r;
      int hcol = hc0 + cloc;
      #pragma unroll
      for (int jj=0; jj<4; ++jj){
        int m = m0 + wr*32 + fm*16 + q*4 + jj;
        float gir = bf2f(gjets[(size_t)m*768 + hcol])       + gm_s[cloc];
        float giz = bf2f(gjets[(size_t)m*768 + 256 + hcol]) + gm_s[64+cloc];
        float gin = bf2f(gjets[(size_t)m*768 + 512 + hcol]) + gm_s[128+cloc];
        float rr = sigmoidf_(gir + acc[0][fm][fn][jj] + bh_s[cloc]);
        float zz = sigmoidf_(giz + acc[1][fm][fn][jj] + bh_s[64+cloc]);
        float nn = tanhf(gin + rr*(acc[2][fm][fn][jj] + bh_s[128+cloc]));
        float ho = bf2f(hbf_in[(size_t)m*256 + hcol]);
        float hn = (1.f - zz)*nn + zz*ho;
        hbf_out[(size_t)m*256 + hcol] = f2bf(hn);
        pacc[fm][jj] = fmaf(wef[fn], hn, pacc[fm][jj]);
      }
    }
  if (compute_s){
    #pragma unroll
    for (int fm=0; fm<2; ++fm)
      #pragma unroll
      for (int jj=0; jj<4; ++jj){
        float p = pacc[fm][jj];
        p += __shfl_xor(p,1); p += __shfl_xor(p,2);
        p += __shfl_xor(p,4); p += __shfl_xor(p,8);
        if (r == 0)
          s_part[(hcb*2 + wc)*8192 + m0 + wr*32 + fm*16 + q*4 + jj] = p;
      }
  }
}

// ---- readout MFMA: slot partial writes. 512 blocks ----
__global__ __launch_bounds__(256) void k_ro(
    const ushort_t* __restrict__ hbf, const ushort_t* __restrict__ Wr1T,
    const float* __restrict__ br1, float* __restrict__ zsum_p)
{
  __shared__ __align__(16) short As[64*APITCH];
  __shared__ __align__(16) short Bs[64*APITCH];
  int t = threadIdx.x;
  int ncb = blockIdx.x & 3, mblk = blockIdx.x >> 2;
  int m0 = mblk*64, nc0 = ncb*64, b = m0 >> 8;
  int lane = t & 63, w = t >> 6;
  int wr = w >> 1, wc = w & 1;
  int q = lane >> 4, r = lane & 15;
  int srow = t >> 2, sseg = t & 3;
  f32x4 acc[2][2] = {};
  for (int kt = 0; kt < 8; ++kt){
    __syncthreads();
    *(uint4*)&As[srow*APITCH + sseg*8] = *(const uint4*)&hbf[(size_t)(m0+srow)*256 + kt*32 + sseg*8];
    *(uint4*)&Bs[srow*APITCH + sseg*8] = *(const uint4*)&Wr1T[(size_t)(nc0+srow)*256 + kt*32 + sseg*8];
    __syncthreads();
    short8 af[2], bfr[2];
    #pragma unroll
    for (int fm=0; fm<2; ++fm)
      af[fm] = *(const short8*)&As[(wr*32 + fm*16 + r)*APITCH + q*8];
    #pragma unroll
    for (int fn=0; fn<2; ++fn)
      bfr[fn] = *(const short8*)&Bs[(wc*32 + fn*16 + r)*APITCH + q*8];
    #pragma unroll
    for (int fm=0; fm<2; ++fm)
      #pragma unroll
      for (int fn=0; fn<2; ++fn)
        acc[fm][fn] = __builtin_amdgcn_mfma_f32_16x16x32_bf16(af[fm], bfr[fn], acc[fm][fn], 0,0,0);
  }
  #pragma unroll
  for (int fn=0; fn<2; ++fn){
    int n = nc0 + wc*32 + fn*16 + r;
    float bb = br1[n];
    float cs = 0.f;
    #pragma unroll
    for (int fm=0; fm<2; ++fm)
      #pragma unroll
      for (int jj=0; jj<4; ++jj)
        cs += fmaxf(acc[fm][fn][jj] + bb, 0.f);
    cs += __shfl_xor(cs, 16);
    cs += __shfl_xor(cs, 32);
    if (q == 0) zsum_p[((mblk&3)*2 + wr)*8192 + b*256 + n] = cs;
  }
}

// ---- final: out[b,:] = (Σ slots zsum)[b,:] @ Wr2 + N*br2. 32 blocks ----
__global__ __launch_bounds__(256) void k_fin(const float* __restrict__ zsum_p,
    const float* __restrict__ Wr2, const float* __restrict__ br2,
    float* __restrict__ out){
  int b = blockIdx.x, t = threadIdx.x;
  __shared__ float zs[256];
  float z = 0.f;
  #pragma unroll
  for (int sl=0; sl<8; ++sl) z += zsum_p[sl*8192 + b*256 + t];
  zs[t] = z; __syncthreads();
  float acc = 0.f;
  for (int k=0;k<256;++k) acc = fmaf(zs[k], Wr2[k*256 + t], acc);
  out[b*256 + t] = acc + 256.0f*br2[t];
}

extern "C" void kernel_launch(void* const* d_in, const int* in_sizes, int n_in,
                              void* d_out, int out_size, void* d_ws, size_t ws_size,
                              hipStream_t stream){
  (void)in_sizes; (void)n_in; (void)out_size; (void)ws_size;
  const float* jets  = (const float*)d_in[0];
  const float* W_emb = (const float*)d_in[1];
  const float* b_emb = (const float*)d_in[2];
  const float* w_edge= (const float*)d_in[3];
  // d_in[4] = b_edge: cancels in softmax
  const float* W_msg = (const float*)d_in[5];
  const float* b_msg = (const float*)d_in[6];
  const float* Wi    = (const float*)d_in[7];
  const float* bi    = (const float*)d_in[8];
  const float* Wh    = (const float*)d_in[9];
  const float* bh    = (const float*)d_in[10];
  const float* Wr1   = (const float*)d_in[11];
  const float* br1   = (const float*)d_in[12];
  const float* Wr2   = (const float*)d_in[13];
  const float* br2   = (const float*)d_in[14];
  float* out = (float*)d_out;
  float* ws  = (float*)d_ws;
  // workspace layout (float-slot units)
  ushort_t* hbf0  = (ushort_t*)ws;                  // 1,048,576 f
  ushort_t* hbf1  = (ushort_t*)(ws + 1048576);      // 1,048,576 f
  ushort_t* gjets = (ushort_t*)(ws + 2097152);      // 3,145,728 f
  float* WiMt     = ws + 5242880;                   // 196,608 (f32 [k=256][row=768])
  ushort_t* WhB   = (ushort_t*)(ws + 5439488);      // 98,304 f
  ushort_t* Wr1T  = (ushort_t*)(ws + 5537792);      // 32,768 f
  float* s_part   = ws + 5570560;                   // [8][8192]
  float* hbar_p   = ws + 5636096;                   // [8][8192]
  float* msg_p    = ws + 5701632;                   // [8][8192]
  float* gmsg_p   = ws + 5767168;                   // [8][24576]
  float* zsum_p   = ws + 5963776;                   // [8][8192] (end 6,029,312 f = 24.1MB)
  ushort_t* hbf[2] = {hbf0, hbf1};

  k_pe<<<512,NT,0,stream>>>(jets, W_emb, b_emb, w_edge, Wi, bi, Wh, Wr1,
                            hbf[0], gjets, WiMt, WhB, Wr1T, s_part);
  for (int it=0; it<3; ++it){
    int cur = it & 1, nxt = cur ^ 1;
    k_hbar<<<256,NT,0,stream>>>(hbf[cur], s_part, hbar_p);
    k_msgp<<<256,NT,0,stream>>>(hbar_p, W_msg, msg_p);
    k_gmsgp<<<256,NT,0,stream>>>(msg_p, b_msg, WiMt, gmsg_p);
    k_gru_mfma<<<512,NT,0,stream>>>(hbf[cur], WhB, bh, gjets, gmsg_p, w_edge,
                                    hbf[nxt], s_part, (it<2)?1:0);
  }
  k_ro<<<512,NT,0,stream>>>(hbf[1], Wr1T, br1, zsum_p);
  k_fin<<<32,NT,0,stream>>>(zsum_p, Wr2, br2, out);
}